// Round 4
// baseline (659.096 us; speedup 1.0000x reference)
//
#include <hip/hip_runtime.h>
#include <hip/hip_bf16.h>

using bf16 = __bf16;
typedef __bf16 bf16x8 __attribute__((ext_vector_type(8)));
typedef __bf16 bf16x4 __attribute__((ext_vector_type(4)));
typedef float  f32x4  __attribute__((ext_vector_type(4)));

// ---------------------------------------------------------------------------
// Prep: one pass over fp32 x -> xb = (bf16)x  and  swb = (bf16)swish(x).
// ---------------------------------------------------------------------------
__global__ void prep(const float* __restrict__ x, bf16* __restrict__ xb,
                     bf16* __restrict__ swb, int n)
{
    int base = (blockIdx.x * 256 + threadIdx.x) * 8;
    if (base >= n) return;
    float4 a = *(const float4*)(x + base);
    float4 b = *(const float4*)(x + base + 4);
    float xs[8] = {a.x, a.y, a.z, a.w, b.x, b.y, b.z, b.w};
    bf16x8 xo, so;
#pragma unroll
    for (int t = 0; t < 8; ++t) {
        xo[t] = (bf16)xs[t];
        so[t] = (bf16)(xs[t] / (1.0f + __expf(-xs[t])));
    }
    *(bf16x8*)(xb  + base) = xo;
    *(bf16x8*)(swb + base) = so;
}

// ---------------------------------------------------------------------------
// Weight transpose + downcast: Wt[n*ldT + k] = (bf16)W[k*N + n]  (fp32 KxN in)
// ---------------------------------------------------------------------------
__global__ void transpose_k(const float* __restrict__ W, bf16* __restrict__ Wt,
                            int K, int N, int ldT, int total)
{
    int idx = blockIdx.x * 256 + threadIdx.x;
    if (idx >= total) return;
    int k = idx % K;
    int n = idx / K;
    Wt[(size_t)n * ldT + k] = (bf16)W[(size_t)k * N + n];
}

// ---------------------------------------------------------------------------
// MFMA GEMM: C(Mx512) = A(MxK) * B(Kx512), Bt: 512 x K bf16 (row-major in K).
//
// Round-1/2/3 lesson: the kernel is LATENCY/TLP-bound, not LDS-BW-bound
// (R2: removing B's LDS round trip -> slower) and not fixable by register
// pipelining (R3: VGPR 120 -> 7 waves/CU -> slower). Occupancy was the
// consistent explanatory variable (41%/40%/21% <-> 194/227/235 us), and R1
// was GRID-capped at 2 blocks/CU. So: keep R1's staging structure exactly
// (batched global->LDS for A+B, single buffer, 2 barriers -> max MLP, low
// VGPR) and raise TLP: tile 64(M) x 128(N), 256 threads = 4 waves (2M x 2N),
// LDS 15.4 KB, grid (M/64)x4 = 2048 = EXACTLY 8 blocks/CU = 32 waves, no
// tail. 8 independent blocks/CU overlap each other's barrier/vmem stalls.
//
// Total B L2 traffic is invariant under the N-split (~1.6 GB for KAN);
// A/x re-reads across the 4 n-tiles of one m-tile hit the same XCD L2 via
// the chunked bid swizzle (4 consecutive bids = same m-tile -> same XCD).
//
// AMODE 0: A bf16, row stride K. AMODE 2 (KAN): logical A = [swish|phi],
// K=3072: k<512 direct bf16x8 from swb; k>=512 phi from fp32 x:
// c=(k-512)/5, g=(k-512)%5, phi=exp(-(x[c]-(g-2))^2); 8-wide chunk spans
// <=3 channels -> 3 scalar loads + shift-register eval. Accumulation order
// (k ascending, 32-chunks) identical to R1 -> bit-identical output.
// ---------------------------------------------------------------------------
template<int AMODE, bool BIAS, typename CT>
__global__ __launch_bounds__(256, 8)
void gemm_bt(const bf16* __restrict__ A, const float* __restrict__ X,
             const bf16* __restrict__ Bt, CT* __restrict__ C,
             int M, int K, const float* __restrict__ bias)
{
    constexpr int LDA = 40;              // 32 + 8 pad: 16B-aligned rows, breaks pow2 stride
    __shared__ bf16 As[64 * LDA];
    __shared__ bf16 Bs[128 * LDA];

    // XCD-chunked bijective bid swizzle (gridDim.x % 8 == 0): each XCD gets a
    // contiguous bid range -> the 4 n-tiles of an m-tile share that XCD's L2.
    const int nwg = gridDim.x;
    const int bid = ((int)blockIdx.x & 7) * (nwg >> 3) + ((int)blockIdx.x >> 3);

    const int tid  = threadIdx.x;
    const int lane = tid & 63;
    const int wave = tid >> 6;           // 0..3
    const int wm   = wave >> 1;          // 0..1: M half
    const int wn   = wave & 1;           // 0..1: N half
    const int quad = lane >> 4;
    const int l15  = lane & 15;
    const int m0   = (bid >> 2) * 64;
    const int n0   = (bid & 3) * 128;

    f32x4 acc[2][4] = {};

    for (int kt = 0; kt < K; kt += 32) {
        // ---- B tile: 128 rows x 32k = 512 chunks of 8 bf16, 2 per thread ----
#pragma unroll
        for (int cc = 0; cc < 2; ++cc) {
            const int chunk = cc * 256 + tid;
            const int row   = chunk >> 2;            // 0..127
            const int col8  = (chunk & 3) * 8;
            *(bf16x8*)(Bs + row * LDA + col8) =
                *(const bf16x8*)(Bt + (size_t)(n0 + row) * K + kt + col8);
        }
        // ---- A tile: 64 rows x 32k = 256 chunks, 1 per thread ----
        {
            const int row  = tid >> 2;               // 0..63
            const int col8 = (tid & 3) * 8;
            if (AMODE == 0) {
                *(bf16x8*)(As + row * LDA + col8) =
                    *(const bf16x8*)(A + (size_t)(m0 + row) * K + kt + col8);
            } else {
                const int kg = kt + col8;
                if (kg < 512) {
                    *(bf16x8*)(As + row * LDA + col8) =
                        *(const bf16x8*)(A + (size_t)(m0 + row) * 512 + kg);
                } else {
                    const int ks = kg - 512;         // chunk starts 0..2552
                    const int c0 = ks / 5;
                    const int r0 = ks - c0 * 5;
                    const float* xr = X + (size_t)(m0 + row) * 512 + c0;
                    const float x0 = xr[0];
                    const float x1 = xr[1];
                    // 3rd channel only needed when c0 <= 509; clamp keeps the
                    // load in-bounds at the buffer tail (value then unused).
                    const float x2v = xr[(c0 < 510) ? 2 : 1];
                    bf16x8 o;
                    float xv = x0, xnext = x1;
                    int g = r0;
#pragma unroll
                    for (int t = 0; t < 8; ++t) {
                        float d = xv - (float)(g - 2);
                        o[t] = (bf16)__expf(-d * d);
                        if (++g == 5) { g = 0; xv = xnext; xnext = x2v; }
                    }
                    *(bf16x8*)(As + row * LDA + col8) = o;
                }
            }
        }
        __syncthreads();

        bf16x8 af[2], bfr[4];
#pragma unroll
        for (int i = 0; i < 2; ++i)
            af[i] = *(const bf16x8*)(As + (wm * 32 + i * 16 + l15) * LDA + quad * 8);
#pragma unroll
        for (int j = 0; j < 4; ++j)
            bfr[j] = *(const bf16x8*)(Bs + (wn * 64 + j * 16 + l15) * LDA + quad * 8);
#pragma unroll
        for (int i = 0; i < 2; ++i)
#pragma unroll
            for (int j = 0; j < 4; ++j)
                acc[i][j] = __builtin_amdgcn_mfma_f32_16x16x32_bf16(af[i], bfr[j], acc[i][j], 0, 0, 0);
        __syncthreads();
    }

    // ---- epilogue: D layout col=lane&15, row=quad*4+reg ----
#pragma unroll
    for (int i = 0; i < 2; ++i) {
#pragma unroll
        for (int j = 0; j < 4; ++j) {
            const int col = n0 + wn * 64 + j * 16 + l15;
            const float bv = BIAS ? bias[col] : 0.0f;
#pragma unroll
            for (int r = 0; r < 4; ++r) {
                const int row = m0 + wm * 32 + i * 16 + quad * 4 + r;
                C[(size_t)row * 512 + col] = (CT)(acc[i][j][r] + bv);
            }
        }
    }
}

// ---------------------------------------------------------------------------
// MFMA attention: one block per (window b, head h), 256 threads = 4 waves.
// Wave w owns S rows [w*16, w*16+16) of the 64x64 score tile.
//   QK^T : A = Q rows (own 16), B-op = K rows read row-major.
//   softmax: D layout col=l15,row=quad*4+r -> each lane holds 4 rows x 4 cols;
//          row-reduce via __shfl_xor 1/2/4/8 (within the 16-lane quad group).
//          Bias via per-head 225-entry LDS table. Normalization deferred.
//   PV   : P (bf16) -> per-wave LDS region -> A-op; V staged TRANSPOSED in
//          LDS (vsT[32][LV]) so B-op is a row-major ds_read_b128.
// Strides LQ=40, LV=72 keep 16B alignment and <=2-way bank aliasing (free).
// ctx aliases q in global memory: each block reads exactly the slice it
// writes, reads are staged to LDS before any write; blocks are disjoint.
// ---------------------------------------------------------------------------
__global__ __launch_bounds__(256)
void attn_mfma(const bf16* __restrict__ q, const bf16* __restrict__ k,
               const bf16* __restrict__ v, const float* __restrict__ bias_table,
               bf16* __restrict__ ctx)
{
    constexpr int LQ = 40;
    constexpr int LV = 72;
    __shared__ bf16 qs[64 * LQ];          // Q tile; reused for ctx re-coalesce
    __shared__ bf16 ks[64 * LQ];
    __shared__ bf16 vsT[32 * LV];         // V transposed: vsT[d][m]
    __shared__ bf16 Pl[4][16 * LV];       // per-wave P (bf16, unnormalized)
    __shared__ float bl[225];             // bias_table[:, h]

    const int bid  = blockIdx.x;
    const int b    = bid >> 4;
    const int h    = bid & 15;
    const int tid  = threadIdx.x;
    const int lane = tid & 63;
    const int w    = tid >> 6;
    const int quad = lane >> 4;
    const int l15  = lane & 15;

    // ---- stage q, k, v (coalesced bf16x8), v transposed via scalar writes ----
    const int n  = tid >> 2;
    const int d0 = (tid & 3) * 8;
    const size_t gbase = ((size_t)(b * 64 + n)) * 512 + h * 32 + d0;
    {
        bf16x8 rq = *(const bf16x8*)(q + gbase);
        bf16x8 rk = *(const bf16x8*)(k + gbase);
        bf16x8 rv = *(const bf16x8*)(v + gbase);
        *(bf16x8*)(qs + n * LQ + d0) = rq;
        *(bf16x8*)(ks + n * LQ + d0) = rk;
#pragma unroll
        for (int t = 0; t < 8; ++t) vsT[(d0 + t) * LV + n] = rv[t];
    }
    if (tid < 225) bl[tid] = bias_table[tid * 16 + h];
    __syncthreads();

    // ---- QK^T: 4 MFMAs -> S rows [w*16, w*16+16), cols [j*16, j*16+16) ----
    f32x4 sacc[4] = {};
    {
        bf16x8 aq = *(const bf16x8*)(qs + (w * 16 + l15) * LQ + quad * 8);
#pragma unroll
        for (int j = 0; j < 4; ++j) {
            bf16x8 bk = *(const bf16x8*)(ks + (j * 16 + l15) * LQ + quad * 8);
            sacc[j] = __builtin_amdgcn_mfma_f32_16x16x32_bf16(aq, bk, sacc[j], 0, 0, 0);
        }
    }

    // ---- bias + scale + wave-parallel softmax (4 rows per lane) ----
    bf16* Pw = Pl[w];
    float inv[4];
    {
        const float scale = 0.17677669529663687f;   // 1/sqrt(32)
#pragma unroll
        for (int r = 0; r < 4; ++r) {
            const int row = w * 16 + quad * 4 + r;
            const int rh = row >> 3, rw = row & 7;
            float pv[4];
            float mx = -1e30f;
#pragma unroll
            for (int j = 0; j < 4; ++j) {
                const int c   = j * 16 + l15;
                const int idx = (rh - (c >> 3) + 7) * 15 + (rw - (c & 7) + 7);
                float s = sacc[j][r] * scale + bl[idx];
                pv[j] = s;
                mx = fmaxf(mx, s);
            }
            mx = fmaxf(mx, __shfl_xor(mx, 1, 64));
            mx = fmaxf(mx, __shfl_xor(mx, 2, 64));
            mx = fmaxf(mx, __shfl_xor(mx, 4, 64));
            mx = fmaxf(mx, __shfl_xor(mx, 8, 64));
            float sum = 0.0f;
#pragma unroll
            for (int j = 0; j < 4; ++j) {
                float e = __expf(pv[j] - mx);
                pv[j] = e;
                sum += e;
            }
            sum += __shfl_xor(sum, 1, 64);
            sum += __shfl_xor(sum, 2, 64);
            sum += __shfl_xor(sum, 4, 64);
            sum += __shfl_xor(sum, 8, 64);
            inv[r] = 1.0f / sum;
#pragma unroll
            for (int j = 0; j < 4; ++j)
                Pw[(quad * 4 + r) * LV + j * 16 + l15] = (bf16)pv[j];
        }
    }

    // ---- PV: ctx rows [w*16, w*16+16) x 32 dims; 4 MFMAs ----
    f32x4 oacc[2] = {};
#pragma unroll
    for (int mc = 0; mc < 2; ++mc) {
        bf16x8 ap = *(const bf16x8*)(Pw + l15 * LV + mc * 32 + quad * 8);
#pragma unroll
        for (int dt = 0; dt < 2; ++dt) {
            bf16x8 bv = *(const bf16x8*)(vsT + (dt * 16 + l15) * LV + mc * 32 + quad * 8);
            oacc[dt] = __builtin_amdgcn_mfma_f32_16x16x32_bf16(ap, bv, oacc[dt], 0, 0, 0);
        }
    }

    // ---- re-coalesce through qs (wave-local rows) + deferred normalize ----
#pragma unroll
    for (int dt = 0; dt < 2; ++dt)
#pragma unroll
        for (int r = 0; r < 4; ++r)
            qs[(w * 16 + quad * 4 + r) * LQ + dt * 16 + l15] = (bf16)(oacc[dt][r] * inv[r]);

    // Each thread's n = tid>>2 lies in its own wave's 16-row span: no barrier.
    bf16x8 ov = *(const bf16x8*)(qs + n * LQ + d0);
    *(bf16x8*)(ctx + gbase) = ov;
}

// ---------------------------------------------------------------------------
// ws layout (bf16 elements) — total 52,690,944 elems = 105.4 MB:
//   0         WqT     512*512
//   262144    WvT     512*512
//   524288    WprojT  512*512
//   786432    WkT     512*3072  (row n = [Wk_base[:,n] | Wk_spline[:,n]])
//   2359296   xb      32768*512 (bf16 x)
//   19136512  q/ctx   32768*512
//   35913728  k       32768*512
// d_out (fp32, 67 MB) doubles as scratch: lower half swb (bf16 swish(x)),
// upper half v (bf16). Both dead before the final GEMM rewrites d_out.
// ---------------------------------------------------------------------------
extern "C" void kernel_launch(void* const* d_in, const int* in_sizes, int n_in,
                              void* d_out, int out_size, void* d_ws, size_t ws_size,
                              hipStream_t stream)
{
    const float* x       = (const float*)d_in[0];
    const float* Wq      = (const float*)d_in[1];
    const float* Wk_base = (const float*)d_in[2];
    const float* Wk_spl  = (const float*)d_in[3];
    const float* Wv      = (const float*)d_in[4];
    const float* Wproj   = (const float*)d_in[5];
    const float* bproj   = (const float*)d_in[6];
    const float* btab    = (const float*)d_in[7];

    bf16* ws  = (bf16*)d_ws;
    bf16* wqT = ws;
    bf16* wvT = ws + 262144;
    bf16* wpT = ws + 524288;
    bf16* wkT = ws + 786432;
    bf16* xb  = ws + 2359296;
    bf16* q   = ws + 19136512;
    bf16* kk  = ws + 35913728;
    bf16* swb = (bf16*)d_out;              // lower half of d_out
    bf16* vv  = (bf16*)d_out + 16777216;   // upper half of d_out
    bf16* ctx = q;                         // reuse q

    prep<<<8192, 256, 0, stream>>>(x, xb, swb, 16777216);

    transpose_k<<<1024, 256, 0, stream>>>(Wq,      wqT,       512,  512, 512,  262144);
    transpose_k<<<1024, 256, 0, stream>>>(Wv,      wvT,       512,  512, 512,  262144);
    transpose_k<<<1024, 256, 0, stream>>>(Wproj,   wpT,       512,  512, 512,  262144);
    transpose_k<<<1024, 256, 0, stream>>>(Wk_base, wkT,       512,  512, 3072, 262144);
    transpose_k<<<5120, 256, 0, stream>>>(Wk_spl,  wkT + 512, 2560, 512, 3072, 1310720);

    // Tile 64x128: grid = (M/64) x 4 n-tiles = 2048 blocks = 8 blocks/CU.
    gemm_bt<0, false, bf16><<<2048, 256, 0, stream>>>(xb,  nullptr, wqT, q,  32768, 512,  nullptr);
    gemm_bt<2, false, bf16><<<2048, 256, 0, stream>>>(swb, x,       wkT, kk, 32768, 3072, nullptr);
    gemm_bt<0, false, bf16><<<2048, 256, 0, stream>>>(xb,  nullptr, wvT, vv, 32768, 512,  nullptr);

    attn_mfma<<<8192, 256, 0, stream>>>(q, kk, vv, btab, ctx);

    gemm_bt<0, true, float><<<2048, 256, 0, stream>>>(ctx, nullptr, wpT, (float*)d_out, 32768, 512, bproj);
}

// Round 5
// 509.795 us; speedup vs baseline: 1.2929x; 1.2929x over previous
//
#include <hip/hip_runtime.h>
#include <hip/hip_bf16.h>

using bf16 = __bf16;
typedef __bf16 bf16x8 __attribute__((ext_vector_type(8)));
typedef __bf16 bf16x4 __attribute__((ext_vector_type(4)));
typedef float  f32x4  __attribute__((ext_vector_type(4)));

// ---------------------------------------------------------------------------
// Prep: one pass over fp32 x -> xb = (bf16)x  and  swb = (bf16)swish(x).
// ---------------------------------------------------------------------------
__global__ void prep(const float* __restrict__ x, bf16* __restrict__ xb,
                     bf16* __restrict__ swb, int n)
{
    int base = (blockIdx.x * 256 + threadIdx.x) * 8;
    if (base >= n) return;
    float4 a = *(const float4*)(x + base);
    float4 b = *(const float4*)(x + base + 4);
    float xs[8] = {a.x, a.y, a.z, a.w, b.x, b.y, b.z, b.w};
    bf16x8 xo, so;
#pragma unroll
    for (int t = 0; t < 8; ++t) {
        xo[t] = (bf16)xs[t];
        so[t] = (bf16)(xs[t] / (1.0f + __expf(-xs[t])));
    }
    *(bf16x8*)(xb  + base) = xo;
    *(bf16x8*)(swb + base) = so;
}

// ---------------------------------------------------------------------------
// Weight transpose + downcast: Wt[n*ldT + k] = (bf16)W[k*N + n]  (fp32 KxN in)
// ---------------------------------------------------------------------------
__global__ void transpose_k(const float* __restrict__ W, bf16* __restrict__ Wt,
                            int K, int N, int ldT, int total)
{
    int idx = blockIdx.x * 256 + threadIdx.x;
    if (idx >= total) return;
    int k = idx % K;
    int n = idx / K;
    Wt[(size_t)n * ldT + k] = (bf16)W[(size_t)k * N + n];
}

// ---------------------------------------------------------------------------
// MFMA GEMM: C(Mx512) = A(MxK) * B(Kx512), Bt: 512 x K bf16 (row-major in K).
//
// R4 post-mortem: __launch_bounds__(256,8) capped the unified VGPR/AGPR
// budget at 64 regs; acc[2][4] (32 AGPRs) + fragments + addressing spilled
// to scratch -> WRITE_SIZE 539 MB (16x output), MfmaUtil 10.7%. The spill,
// not the structure, was the regression. Occupancy itself DID rise to 76%.
//
// R5: identical structure, __launch_bounds__(256,4) (128-reg budget, no
// spills, ~5-6 blocks/CU resident). Tile 64(M) x 128(N), 256 threads =
// 4 waves (2M x 2N), LDS 15.4 KB, grid (M/64)x4 = 2048 -> many independent
// small blocks per CU overlap each other's barrier/vmem stalls (the R1->R4
// TLP lever, now without the register cliff).
//
// B L2 traffic invariant under N-split; A/x re-reads across the 4 n-tiles
// of an m-tile hit the same XCD L2 via the chunked bid swizzle.
//
// AMODE 0: A bf16, row stride K. AMODE 2 (KAN): logical A = [swish|phi],
// K=3072: k<512 direct bf16x8 from swb; k>=512 phi from fp32 x:
// c=(k-512)/5, g=(k-512)%5, phi=exp(-(x[c]-(g-2))^2); 8-wide chunk spans
// <=3 channels -> 3 scalar loads + shift-register eval. Accumulation order
// (k ascending, 32-chunks) identical to R1 -> bit-identical output.
// ---------------------------------------------------------------------------
template<int AMODE, bool BIAS, typename CT>
__global__ __launch_bounds__(256, 4)
void gemm_bt(const bf16* __restrict__ A, const float* __restrict__ X,
             const bf16* __restrict__ Bt, CT* __restrict__ C,
             int M, int K, const float* __restrict__ bias)
{
    constexpr int LDA = 40;              // 32 + 8 pad: 16B-aligned rows, breaks pow2 stride
    __shared__ bf16 As[64 * LDA];
    __shared__ bf16 Bs[128 * LDA];

    // XCD-chunked bijective bid swizzle (gridDim.x % 8 == 0): each XCD gets a
    // contiguous bid range -> the 4 n-tiles of an m-tile share that XCD's L2.
    const int nwg = gridDim.x;
    const int bid = ((int)blockIdx.x & 7) * (nwg >> 3) + ((int)blockIdx.x >> 3);

    const int tid  = threadIdx.x;
    const int lane = tid & 63;
    const int wave = tid >> 6;           // 0..3
    const int wm   = wave >> 1;          // 0..1: M half
    const int wn   = wave & 1;           // 0..1: N half
    const int quad = lane >> 4;
    const int l15  = lane & 15;
    const int m0   = (bid >> 2) * 64;
    const int n0   = (bid & 3) * 128;

    f32x4 acc[2][4] = {};

    for (int kt = 0; kt < K; kt += 32) {
        // ---- B tile: 128 rows x 32k = 512 chunks of 8 bf16, 2 per thread ----
#pragma unroll
        for (int cc = 0; cc < 2; ++cc) {
            const int chunk = cc * 256 + tid;
            const int row   = chunk >> 2;            // 0..127
            const int col8  = (chunk & 3) * 8;
            *(bf16x8*)(Bs + row * LDA + col8) =
                *(const bf16x8*)(Bt + (size_t)(n0 + row) * K + kt + col8);
        }
        // ---- A tile: 64 rows x 32k = 256 chunks, 1 per thread ----
        {
            const int row  = tid >> 2;               // 0..63
            const int col8 = (tid & 3) * 8;
            if (AMODE == 0) {
                *(bf16x8*)(As + row * LDA + col8) =
                    *(const bf16x8*)(A + (size_t)(m0 + row) * K + kt + col8);
            } else {
                const int kg = kt + col8;
                if (kg < 512) {
                    *(bf16x8*)(As + row * LDA + col8) =
                        *(const bf16x8*)(A + (size_t)(m0 + row) * 512 + kg);
                } else {
                    const int ks = kg - 512;         // chunk starts 0..2552
                    const int c0 = ks / 5;
                    const int r0 = ks - c0 * 5;
                    const float* xr = X + (size_t)(m0 + row) * 512 + c0;
                    const float x0 = xr[0];
                    const float x1 = xr[1];
                    // 3rd channel only needed when c0 <= 509; clamp keeps the
                    // load in-bounds at the buffer tail (value then unused).
                    const float x2v = xr[(c0 < 510) ? 2 : 1];
                    bf16x8 o;
                    float xv = x0, xnext = x1;
                    int g = r0;
#pragma unroll
                    for (int t = 0; t < 8; ++t) {
                        float d = xv - (float)(g - 2);
                        o[t] = (bf16)__expf(-d * d);
                        if (++g == 5) { g = 0; xv = xnext; xnext = x2v; }
                    }
                    *(bf16x8*)(As + row * LDA + col8) = o;
                }
            }
        }
        __syncthreads();

        bf16x8 af[2], bfr[4];
#pragma unroll
        for (int i = 0; i < 2; ++i)
            af[i] = *(const bf16x8*)(As + (wm * 32 + i * 16 + l15) * LDA + quad * 8);
#pragma unroll
        for (int j = 0; j < 4; ++j)
            bfr[j] = *(const bf16x8*)(Bs + (wn * 64 + j * 16 + l15) * LDA + quad * 8);
#pragma unroll
        for (int i = 0; i < 2; ++i)
#pragma unroll
            for (int j = 0; j < 4; ++j)
                acc[i][j] = __builtin_amdgcn_mfma_f32_16x16x32_bf16(af[i], bfr[j], acc[i][j], 0, 0, 0);
        __syncthreads();
    }

    // ---- epilogue: D layout col=lane&15, row=quad*4+reg ----
#pragma unroll
    for (int i = 0; i < 2; ++i) {
#pragma unroll
        for (int j = 0; j < 4; ++j) {
            const int col = n0 + wn * 64 + j * 16 + l15;
            const float bv = BIAS ? bias[col] : 0.0f;
#pragma unroll
            for (int r = 0; r < 4; ++r) {
                const int row = m0 + wm * 32 + i * 16 + quad * 4 + r;
                C[(size_t)row * 512 + col] = (CT)(acc[i][j][r] + bv);
            }
        }
    }
}

// ---------------------------------------------------------------------------
// MFMA attention: one block per (window b, head h), 256 threads = 4 waves.
// Wave w owns S rows [w*16, w*16+16) of the 64x64 score tile.
//   QK^T : A = Q rows (own 16), B-op = K rows read row-major.
//   softmax: D layout col=l15,row=quad*4+r -> each lane holds 4 rows x 4 cols;
//          row-reduce via __shfl_xor 1/2/4/8 (within the 16-lane quad group).
//          Bias via per-head 225-entry LDS table. Normalization deferred.
//   PV   : P (bf16) -> per-wave LDS region -> A-op; V staged TRANSPOSED in
//          LDS (vsT[32][LV]) so B-op is a row-major ds_read_b128.
// Strides LQ=40, LV=72 keep 16B alignment and <=2-way bank aliasing (free).
// ctx aliases q in global memory: each block reads exactly the slice it
// writes, reads are staged to LDS before any write; blocks are disjoint.
// ---------------------------------------------------------------------------
__global__ __launch_bounds__(256)
void attn_mfma(const bf16* __restrict__ q, const bf16* __restrict__ k,
               const bf16* __restrict__ v, const float* __restrict__ bias_table,
               bf16* __restrict__ ctx)
{
    constexpr int LQ = 40;
    constexpr int LV = 72;
    __shared__ bf16 qs[64 * LQ];          // Q tile; reused for ctx re-coalesce
    __shared__ bf16 ks[64 * LQ];
    __shared__ bf16 vsT[32 * LV];         // V transposed: vsT[d][m]
    __shared__ bf16 Pl[4][16 * LV];       // per-wave P (bf16, unnormalized)
    __shared__ float bl[225];             // bias_table[:, h]

    const int bid  = blockIdx.x;
    const int b    = bid >> 4;
    const int h    = bid & 15;
    const int tid  = threadIdx.x;
    const int lane = tid & 63;
    const int w    = tid >> 6;
    const int quad = lane >> 4;
    const int l15  = lane & 15;

    // ---- stage q, k, v (coalesced bf16x8), v transposed via scalar writes ----
    const int n  = tid >> 2;
    const int d0 = (tid & 3) * 8;
    const size_t gbase = ((size_t)(b * 64 + n)) * 512 + h * 32 + d0;
    {
        bf16x8 rq = *(const bf16x8*)(q + gbase);
        bf16x8 rk = *(const bf16x8*)(k + gbase);
        bf16x8 rv = *(const bf16x8*)(v + gbase);
        *(bf16x8*)(qs + n * LQ + d0) = rq;
        *(bf16x8*)(ks + n * LQ + d0) = rk;
#pragma unroll
        for (int t = 0; t < 8; ++t) vsT[(d0 + t) * LV + n] = rv[t];
    }
    if (tid < 225) bl[tid] = bias_table[tid * 16 + h];
    __syncthreads();

    // ---- QK^T: 4 MFMAs -> S rows [w*16, w*16+16), cols [j*16, j*16+16) ----
    f32x4 sacc[4] = {};
    {
        bf16x8 aq = *(const bf16x8*)(qs + (w * 16 + l15) * LQ + quad * 8);
#pragma unroll
        for (int j = 0; j < 4; ++j) {
            bf16x8 bk = *(const bf16x8*)(ks + (j * 16 + l15) * LQ + quad * 8);
            sacc[j] = __builtin_amdgcn_mfma_f32_16x16x32_bf16(aq, bk, sacc[j], 0, 0, 0);
        }
    }

    // ---- bias + scale + wave-parallel softmax (4 rows per lane) ----
    bf16* Pw = Pl[w];
    float inv[4];
    {
        const float scale = 0.17677669529663687f;   // 1/sqrt(32)
#pragma unroll
        for (int r = 0; r < 4; ++r) {
            const int row = w * 16 + quad * 4 + r;
            const int rh = row >> 3, rw = row & 7;
            float pv[4];
            float mx = -1e30f;
#pragma unroll
            for (int j = 0; j < 4; ++j) {
                const int c   = j * 16 + l15;
                const int idx = (rh - (c >> 3) + 7) * 15 + (rw - (c & 7) + 7);
                float s = sacc[j][r] * scale + bl[idx];
                pv[j] = s;
                mx = fmaxf(mx, s);
            }
            mx = fmaxf(mx, __shfl_xor(mx, 1, 64));
            mx = fmaxf(mx, __shfl_xor(mx, 2, 64));
            mx = fmaxf(mx, __shfl_xor(mx, 4, 64));
            mx = fmaxf(mx, __shfl_xor(mx, 8, 64));
            float sum = 0.0f;
#pragma unroll
            for (int j = 0; j < 4; ++j) {
                float e = __expf(pv[j] - mx);
                pv[j] = e;
                sum += e;
            }
            sum += __shfl_xor(sum, 1, 64);
            sum += __shfl_xor(sum, 2, 64);
            sum += __shfl_xor(sum, 4, 64);
            sum += __shfl_xor(sum, 8, 64);
            inv[r] = 1.0f / sum;
#pragma unroll
            for (int j = 0; j < 4; ++j)
                Pw[(quad * 4 + r) * LV + j * 16 + l15] = (bf16)pv[j];
        }
    }

    // ---- PV: ctx rows [w*16, w*16+16) x 32 dims; 4 MFMAs ----
    f32x4 oacc[2] = {};
#pragma unroll
    for (int mc = 0; mc < 2; ++mc) {
        bf16x8 ap = *(const bf16x8*)(Pw + l15 * LV + mc * 32 + quad * 8);
#pragma unroll
        for (int dt = 0; dt < 2; ++dt) {
            bf16x8 bv = *(const bf16x8*)(vsT + (dt * 16 + l15) * LV + mc * 32 + quad * 8);
            oacc[dt] = __builtin_amdgcn_mfma_f32_16x16x32_bf16(ap, bv, oacc[dt], 0, 0, 0);
        }
    }

    // ---- re-coalesce through qs (wave-local rows) + deferred normalize ----
#pragma unroll
    for (int dt = 0; dt < 2; ++dt)
#pragma unroll
        for (int r = 0; r < 4; ++r)
            qs[(w * 16 + quad * 4 + r) * LQ + dt * 16 + l15] = (bf16)(oacc[dt][r] * inv[r]);

    // Each thread's n = tid>>2 lies in its own wave's 16-row span: no barrier.
    bf16x8 ov = *(const bf16x8*)(qs + n * LQ + d0);
    *(bf16x8*)(ctx + gbase) = ov;
}

// ---------------------------------------------------------------------------
// ws layout (bf16 elements) — total 52,690,944 elems = 105.4 MB:
//   0         WqT     512*512
//   262144    WvT     512*512
//   524288    WprojT  512*512
//   786432    WkT     512*3072  (row n = [Wk_base[:,n] | Wk_spline[:,n]])
//   2359296   xb      32768*512 (bf16 x)
//   19136512  q/ctx   32768*512
//   35913728  k       32768*512
// d_out (fp32, 67 MB) doubles as scratch: lower half swb (bf16 swish(x)),
// upper half v (bf16). Both dead before the final GEMM rewrites d_out.
// ---------------------------------------------------------------------------
extern "C" void kernel_launch(void* const* d_in, const int* in_sizes, int n_in,
                              void* d_out, int out_size, void* d_ws, size_t ws_size,
                              hipStream_t stream)
{
    const float* x       = (const float*)d_in[0];
    const float* Wq      = (const float*)d_in[1];
    const float* Wk_base = (const float*)d_in[2];
    const float* Wk_spl  = (const float*)d_in[3];
    const float* Wv      = (const float*)d_in[4];
    const float* Wproj   = (const float*)d_in[5];
    const float* bproj   = (const float*)d_in[6];
    const float* btab    = (const float*)d_in[7];

    bf16* ws  = (bf16*)d_ws;
    bf16* wqT = ws;
    bf16* wvT = ws + 262144;
    bf16* wpT = ws + 524288;
    bf16* wkT = ws + 786432;
    bf16* xb  = ws + 2359296;
    bf16* q   = ws + 19136512;
    bf16* kk  = ws + 35913728;
    bf16* swb = (bf16*)d_out;              // lower half of d_out
    bf16* vv  = (bf16*)d_out + 16777216;   // upper half of d_out
    bf16* ctx = q;                         // reuse q

    prep<<<8192, 256, 0, stream>>>(x, xb, swb, 16777216);

    transpose_k<<<1024, 256, 0, stream>>>(Wq,      wqT,       512,  512, 512,  262144);
    transpose_k<<<1024, 256, 0, stream>>>(Wv,      wvT,       512,  512, 512,  262144);
    transpose_k<<<1024, 256, 0, stream>>>(Wproj,   wpT,       512,  512, 512,  262144);
    transpose_k<<<1024, 256, 0, stream>>>(Wk_base, wkT,       512,  512, 3072, 262144);
    transpose_k<<<5120, 256, 0, stream>>>(Wk_spl,  wkT + 512, 2560, 512, 3072, 1310720);

    // Tile 64x128: grid = (M/64) x 4 n-tiles = 2048 blocks.
    gemm_bt<0, false, bf16><<<2048, 256, 0, stream>>>(xb,  nullptr, wqT, q,  32768, 512,  nullptr);
    gemm_bt<2, false, bf16><<<2048, 256, 0, stream>>>(swb, x,       wkT, kk, 32768, 3072, nullptr);
    gemm_bt<0, false, bf16><<<2048, 256, 0, stream>>>(xb,  nullptr, wvT, vv, 32768, 512,  nullptr);

    attn_mfma<<<8192, 256, 0, stream>>>(q, kk, vv, btab, ctx);

    gemm_bt<0, true, float><<<2048, 256, 0, stream>>>(ctx, nullptr, wpT, (float*)d_out, 32768, 512, bproj);
}

// Round 6
// 418.986 us; speedup vs baseline: 1.5731x; 1.2167x over previous
//
#include <hip/hip_runtime.h>
#include <hip/hip_bf16.h>

using bf16 = __bf16;
typedef __bf16 bf16x8 __attribute__((ext_vector_type(8)));
typedef __bf16 bf16x4 __attribute__((ext_vector_type(4)));
typedef float  f32x4  __attribute__((ext_vector_type(4)));

// Async global->LDS DMA, 16B per lane. LDS dest must be wave-uniform base +
// lane*16 (linear, no padding); global src is per-lane. Guide m97: the
// compiler NEVER auto-emits this; width 4->16 alone was +67% there.
__device__ __forceinline__ void gl2lds16(const bf16* g, bf16* l)
{
    __builtin_amdgcn_global_load_lds(
        (const __attribute__((address_space(1))) unsigned int*)g,
        (__attribute__((address_space(3))) unsigned int*)l,
        16, 0, 0);
}

// ---------------------------------------------------------------------------
// Prep: one pass over fp32 x -> xb = (bf16)x  and  swb = (bf16)swish(x).
// ---------------------------------------------------------------------------
__global__ void prep(const float* __restrict__ x, bf16* __restrict__ xb,
                     bf16* __restrict__ swb, int n)
{
    int base = (blockIdx.x * 256 + threadIdx.x) * 8;
    if (base >= n) return;
    float4 a = *(const float4*)(x + base);
    float4 b = *(const float4*)(x + base + 4);
    float xs[8] = {a.x, a.y, a.z, a.w, b.x, b.y, b.z, b.w};
    bf16x8 xo, so;
#pragma unroll
    for (int t = 0; t < 8; ++t) {
        xo[t] = (bf16)xs[t];
        so[t] = (bf16)(xs[t] / (1.0f + __expf(-xs[t])));
    }
    *(bf16x8*)(xb  + base) = xo;
    *(bf16x8*)(swb + base) = so;
}

// ---------------------------------------------------------------------------
// Weight transpose + downcast: Wt[n*ldT + k] = (bf16)W[k*N + n]  (fp32 KxN in)
// ---------------------------------------------------------------------------
__global__ void transpose_k(const float* __restrict__ W, bf16* __restrict__ Wt,
                            int K, int N, int ldT, int total)
{
    int idx = blockIdx.x * 256 + threadIdx.x;
    if (idx >= total) return;
    int k = idx % K;
    int n = idx / K;
    Wt[(size_t)n * ldT + k] = (bf16)W[(size_t)k * N + n];
}

// ---------------------------------------------------------------------------
// MFMA GEMM, full-N tiling (R1 structure, the 5-round best): C(Mx512) =
// A(MxK) * B(Kx512), Bt: 512 x K bf16. Tile 64(M) x 512(N), BK=32,
// 512 threads = 8 waves; wave w owns the 64x64 subtile at cols w*64
// (4x4 accs of 16x16x32 MFMA). Full-N: phi computed exactly once.
//
// R2-R5 lessons: TLP/occupancy was NOT the lever (41/52/76% occ all lost to
// R1); staging work per MFMA is. R6 removes the reg-staging round trip
// (Common-mistake #1): B (pure copy, 4 chunks/thread) and the copyable part
// of A go through global_load_lds width-16 -> no VGPR round trip, no
// address-VALU, no lgkmcnt chain. LDS is LINEAR (gload_lds requires
// contiguous dest); b128 reads at 64B row stride are bank-balanced
// (8 words/bank = minimum). __syncthreads' vmcnt drain covers correctness.
//
// AMODE 0: A bf16, row stride K. AMODE 2 (KAN): logical A = [swish|phi],
// K=3072: kt<512 direct copy from swb (gload_lds); kt>=512 phi from fp32 x:
// c=(k-512)/5, g=(k-512)%5, phi=exp(-(x[c]-(g-2))^2), reg-computed +
// ds_write (8-wide chunk spans <=3 channels -> 3 scalar loads).
// Accumulation order (k ascending 32-chunks) identical -> bit-identical.
// ---------------------------------------------------------------------------
template<int AMODE, bool BIAS, typename CT>
__global__ __launch_bounds__(512, 4)
void gemm_bt(const bf16* __restrict__ A, const float* __restrict__ X,
             const bf16* __restrict__ Bt, CT* __restrict__ C,
             int M, int K, const float* __restrict__ bias)
{
    __shared__ bf16 As[64 * 32];          // linear: row stride 32 elems (64 B)
    __shared__ bf16 Bs[512 * 32];

    const int tid  = threadIdx.x;
    const int lane = tid & 63;
    const int wave = tid >> 6;
    const int quad = lane >> 4;
    const int l15  = lane & 15;
    const int m0   = blockIdx.x * 64;

    f32x4 acc[4][4] = {};

    for (int kt = 0; kt < K; kt += 32) {
        // ---- B tile: 512 rows x 32k = 2048 chunks of 16B, 4 per thread,
        //      async DMA (chunk -> Bs byte offset chunk*16, wave-contiguous) ----
#pragma unroll
        for (int cc = 0; cc < 4; ++cc) {
            const int chunk = cc * 512 + tid;
            const int row   = chunk >> 2;
            const int col8  = (chunk & 3) * 8;
            gl2lds16(Bt + (size_t)row * K + kt + col8, Bs + chunk * 8);
        }
        // ---- A tile: 64 rows x 32k = 256 chunks, waves 0..3 ----
        if (AMODE == 0 || kt < 512) {
            if (tid < 256) {
                const int row  = tid >> 2;
                const int col8 = (tid & 3) * 8;
                const int ld   = (AMODE == 0) ? K : 512;
                gl2lds16(A + (size_t)(m0 + row) * ld + kt + col8, As + tid * 8);
            }
        } else {
            if (tid < 256) {
                const int row  = tid >> 2;           // 0..63
                const int col8 = (tid & 3) * 8;
                const int ks = kt + col8 - 512;      // chunk starts 0..2552
                const int c0 = ks / 5;
                const int r0 = ks - c0 * 5;
                const float* xr = X + (size_t)(m0 + row) * 512 + c0;
                const float x0 = xr[0];
                const float x1 = xr[1];
                // 3rd channel only needed when c0 <= 509; clamp keeps the
                // load in-bounds at the buffer tail (value then unused).
                const float x2v = xr[(c0 < 510) ? 2 : 1];
                bf16x8 o;
                float xv = x0, xnext = x1;
                int g = r0;
#pragma unroll
                for (int t = 0; t < 8; ++t) {
                    float d = xv - (float)(g - 2);
                    o[t] = (bf16)__expf(-d * d);
                    if (++g == 5) { g = 0; xv = xnext; xnext = x2v; }
                }
                *(bf16x8*)(As + row * 32 + col8) = o;
            }
        }
        // Barrier drains vmcnt(0)+lgkmcnt(0): all DMA and ds_writes visible.
        __syncthreads();

        bf16x8 af[4], bfr[4];
#pragma unroll
        for (int i = 0; i < 4; ++i)
            af[i] = *(const bf16x8*)(As + (i * 16 + l15) * 32 + quad * 8);
#pragma unroll
        for (int j = 0; j < 4; ++j)
            bfr[j] = *(const bf16x8*)(Bs + (wave * 64 + j * 16 + l15) * 32 + quad * 8);
#pragma unroll
        for (int i = 0; i < 4; ++i)
#pragma unroll
            for (int j = 0; j < 4; ++j)
                acc[i][j] = __builtin_amdgcn_mfma_f32_16x16x32_bf16(af[i], bfr[j], acc[i][j], 0, 0, 0);
        __syncthreads();
    }

    // ---- epilogue: D layout col=lane&15, row=quad*4+reg ----
#pragma unroll
    for (int i = 0; i < 4; ++i) {
#pragma unroll
        for (int j = 0; j < 4; ++j) {
            const int col = wave * 64 + j * 16 + l15;
            const float bv = BIAS ? bias[col] : 0.0f;
#pragma unroll
            for (int r = 0; r < 4; ++r) {
                const int row = m0 + i * 16 + quad * 4 + r;
                C[(size_t)row * 512 + col] = (CT)(acc[i][j][r] + bv);
            }
        }
    }
}

// ---------------------------------------------------------------------------
// MFMA attention: one block per (window b, head h), 256 threads = 4 waves.
// Wave w owns S rows [w*16, w*16+16) of the 64x64 score tile.
//   QK^T : A = Q rows (own 16), B-op = K rows read row-major.
//   softmax: D layout col=l15,row=quad*4+r -> each lane holds 4 rows x 4 cols;
//          row-reduce via __shfl_xor 1/2/4/8 (within the 16-lane quad group).
//          Bias via per-head 225-entry LDS table. Normalization deferred.
//   PV   : P (bf16) -> per-wave LDS region -> A-op; V staged TRANSPOSED in
//          LDS (vsT[32][LV]) so B-op is a row-major ds_read_b128.
// Strides LQ=40, LV=72 keep 16B alignment and <=2-way bank aliasing (free).
// ctx aliases q in global memory: each block reads exactly the slice it
// writes, reads are staged to LDS before any write; blocks are disjoint.
// ---------------------------------------------------------------------------
__global__ __launch_bounds__(256)
void attn_mfma(const bf16* __restrict__ q, const bf16* __restrict__ k,
               const bf16* __restrict__ v, const float* __restrict__ bias_table,
               bf16* __restrict__ ctx)
{
    constexpr int LQ = 40;
    constexpr int LV = 72;
    __shared__ bf16 qs[64 * LQ];          // Q tile; reused for ctx re-coalesce
    __shared__ bf16 ks[64 * LQ];
    __shared__ bf16 vsT[32 * LV];         // V transposed: vsT[d][m]
    __shared__ bf16 Pl[4][16 * LV];       // per-wave P (bf16, unnormalized)
    __shared__ float bl[225];             // bias_table[:, h]

    const int bid  = blockIdx.x;
    const int b    = bid >> 4;
    const int h    = bid & 15;
    const int tid  = threadIdx.x;
    const int lane = tid & 63;
    const int w    = tid >> 6;
    const int quad = lane >> 4;
    const int l15  = lane & 15;

    // ---- stage q, k, v (coalesced bf16x8), v transposed via scalar writes ----
    const int n  = tid >> 2;
    const int d0 = (tid & 3) * 8;
    const size_t gbase = ((size_t)(b * 64 + n)) * 512 + h * 32 + d0;
    {
        bf16x8 rq = *(const bf16x8*)(q + gbase);
        bf16x8 rk = *(const bf16x8*)(k + gbase);
        bf16x8 rv = *(const bf16x8*)(v + gbase);
        *(bf16x8*)(qs + n * LQ + d0) = rq;
        *(bf16x8*)(ks + n * LQ + d0) = rk;
#pragma unroll
        for (int t = 0; t < 8; ++t) vsT[(d0 + t) * LV + n] = rv[t];
    }
    if (tid < 225) bl[tid] = bias_table[tid * 16 + h];
    __syncthreads();

    // ---- QK^T: 4 MFMAs -> S rows [w*16, w*16+16), cols [j*16, j*16+16) ----
    f32x4 sacc[4] = {};
    {
        bf16x8 aq = *(const bf16x8*)(qs + (w * 16 + l15) * LQ + quad * 8);
#pragma unroll
        for (int j = 0; j < 4; ++j) {
            bf16x8 bk = *(const bf16x8*)(ks + (j * 16 + l15) * LQ + quad * 8);
            sacc[j] = __builtin_amdgcn_mfma_f32_16x16x32_bf16(aq, bk, sacc[j], 0, 0, 0);
        }
    }

    // ---- bias + scale + wave-parallel softmax (4 rows per lane) ----
    bf16* Pw = Pl[w];
    float inv[4];
    {
        const float scale = 0.17677669529663687f;   // 1/sqrt(32)
#pragma unroll
        for (int r = 0; r < 4; ++r) {
            const int row = w * 16 + quad * 4 + r;
            const int rh = row >> 3, rw = row & 7;
            float pv[4];
            float mx = -1e30f;
#pragma unroll
            for (int j = 0; j < 4; ++j) {
                const int c   = j * 16 + l15;
                const int idx = (rh - (c >> 3) + 7) * 15 + (rw - (c & 7) + 7);
                float s = sacc[j][r] * scale + bl[idx];
                pv[j] = s;
                mx = fmaxf(mx, s);
            }
            mx = fmaxf(mx, __shfl_xor(mx, 1, 64));
            mx = fmaxf(mx, __shfl_xor(mx, 2, 64));
            mx = fmaxf(mx, __shfl_xor(mx, 4, 64));
            mx = fmaxf(mx, __shfl_xor(mx, 8, 64));
            float sum = 0.0f;
#pragma unroll
            for (int j = 0; j < 4; ++j) {
                float e = __expf(pv[j] - mx);
                pv[j] = e;
                sum += e;
            }
            sum += __shfl_xor(sum, 1, 64);
            sum += __shfl_xor(sum, 2, 64);
            sum += __shfl_xor(sum, 4, 64);
            sum += __shfl_xor(sum, 8, 64);
            inv[r] = 1.0f / sum;
#pragma unroll
            for (int j = 0; j < 4; ++j)
                Pw[(quad * 4 + r) * LV + j * 16 + l15] = (bf16)pv[j];
        }
    }

    // ---- PV: ctx rows [w*16, w*16+16) x 32 dims; 4 MFMAs ----
    f32x4 oacc[2] = {};
#pragma unroll
    for (int mc = 0; mc < 2; ++mc) {
        bf16x8 ap = *(const bf16x8*)(Pw + l15 * LV + mc * 32 + quad * 8);
#pragma unroll
        for (int dt = 0; dt < 2; ++dt) {
            bf16x8 bv = *(const bf16x8*)(vsT + (dt * 16 + l15) * LV + mc * 32 + quad * 8);
            oacc[dt] = __builtin_amdgcn_mfma_f32_16x16x32_bf16(ap, bv, oacc[dt], 0, 0, 0);
        }
    }

    // ---- re-coalesce through qs (wave-local rows) + deferred normalize ----
#pragma unroll
    for (int dt = 0; dt < 2; ++dt)
#pragma unroll
        for (int r = 0; r < 4; ++r)
            qs[(w * 16 + quad * 4 + r) * LQ + dt * 16 + l15] = (bf16)(oacc[dt][r] * inv[r]);

    // Each thread's n = tid>>2 lies in its own wave's 16-row span: no barrier.
    bf16x8 ov = *(const bf16x8*)(qs + n * LQ + d0);
    *(bf16x8*)(ctx + gbase) = ov;
}

// ---------------------------------------------------------------------------
// ws layout (bf16 elements) — total 52,690,944 elems = 105.4 MB:
//   0         WqT     512*512
//   262144    WvT     512*512
//   524288    WprojT  512*512
//   786432    WkT     512*3072  (row n = [Wk_base[:,n] | Wk_spline[:,n]])
//   2359296   xb      32768*512 (bf16 x)
//   19136512  q/ctx   32768*512
//   35913728  k       32768*512
// d_out (fp32, 67 MB) doubles as scratch: lower half swb (bf16 swish(x)),
// upper half v (bf16). Both dead before the final GEMM rewrites d_out.
// ---------------------------------------------------------------------------
extern "C" void kernel_launch(void* const* d_in, const int* in_sizes, int n_in,
                              void* d_out, int out_size, void* d_ws, size_t ws_size,
                              hipStream_t stream)
{
    const float* x       = (const float*)d_in[0];
    const float* Wq      = (const float*)d_in[1];
    const float* Wk_base = (const float*)d_in[2];
    const float* Wk_spl  = (const float*)d_in[3];
    const float* Wv      = (const float*)d_in[4];
    const float* Wproj   = (const float*)d_in[5];
    const float* bproj   = (const float*)d_in[6];
    const float* btab    = (const float*)d_in[7];

    bf16* ws  = (bf16*)d_ws;
    bf16* wqT = ws;
    bf16* wvT = ws + 262144;
    bf16* wpT = ws + 524288;
    bf16* wkT = ws + 786432;
    bf16* xb  = ws + 2359296;
    bf16* q   = ws + 19136512;
    bf16* kk  = ws + 35913728;
    bf16* swb = (bf16*)d_out;              // lower half of d_out
    bf16* vv  = (bf16*)d_out + 16777216;   // upper half of d_out
    bf16* ctx = q;                         // reuse q

    prep<<<8192, 256, 0, stream>>>(x, xb, swb, 16777216);

    transpose_k<<<1024, 256, 0, stream>>>(Wq,      wqT,       512,  512, 512,  262144);
    transpose_k<<<1024, 256, 0, stream>>>(Wv,      wvT,       512,  512, 512,  262144);
    transpose_k<<<1024, 256, 0, stream>>>(Wproj,   wpT,       512,  512, 512,  262144);
    transpose_k<<<1024, 256, 0, stream>>>(Wk_base, wkT,       512,  512, 3072, 262144);
    transpose_k<<<5120, 256, 0, stream>>>(Wk_spl,  wkT + 512, 2560, 512, 3072, 1310720);

    // Full-N tiling: grid = M/64 = 512 blocks, 512 threads (R1 structure).
    gemm_bt<0, false, bf16><<<512, 512, 0, stream>>>(xb,  nullptr, wqT, q,  32768, 512,  nullptr);
    gemm_bt<2, false, bf16><<<512, 512, 0, stream>>>(swb, x,       wkT, kk, 32768, 3072, nullptr);
    gemm_bt<0, false, bf16><<<512, 512, 0, stream>>>(xb,  nullptr, wvT, vv, 32768, 512,  nullptr);

    attn_mfma<<<8192, 256, 0, stream>>>(q, kk, vv, btab, ctx);

    gemm_bt<0, true, float><<<512, 512, 0, stream>>>(ctx, nullptr, wpT, (float*)d_out, 32768, 512, bproj);
}